// Round 8
// baseline (584.512 us; speedup 1.0000x reference)
//
#include <hip/hip_runtime.h>
#include <hip/hip_fp16.h>
#include <math.h>

#define NITERS 50

typedef _Float16 half8 __attribute__((ext_vector_type(8)));  // 4 VGPR MFMA A/B operand
typedef float    f32x4 __attribute__((ext_vector_type(4)));  // MFMA C/D

// One workgroup per batch. K0 built once in LDS (XOR-swizzled rows), then each
// wave stages persistent MFMA A-fragments: 2 row-blocks of K (for s = K*b) and
// 2 col-blocks of K^T (for s2 = K^T*a). b/a are replicated across the 16 MFMA
// B-columns, so each 16x16x32 MFMA chain computes 16 dot products on the
// matrix pipe; the VALU does only powf + stores. 2 barriers/iter. u=v=0
// throughout (rescale provably never fires early; absorption exact:
// K_fin = K0*a_i*b_j, C recovered as -0.1*ln(K0)).
__global__ __launch_bounds__(512, 2) void wfr_kernel(const float* __restrict__ D,
                                                     float* __restrict__ out) {
    __shared__ __align__(16) __half Ksh[256 * 256];   // 128 KiB (build+stage only)
    __shared__ __align__(16) float  sh_bf[256];
    __shared__ __align__(16) float  sh_af[256];
    __shared__ __align__(16) float  sh_s2[256];
    __shared__ __align__(16) __half sh_bh[256];
    __shared__ __align__(16) __half sh_ah[256];
    __shared__ __align__(16) float  part[8];

    const int tid = threadIdx.x;
    const int bb  = blockIdx.x;
    char* Kbytes  = reinterpret_cast<char*>(Ksh);

    // ---- build K0 = exp(-C/eps) = c^20,  c = cos(min(2D, pi/2)) + 1e-5 ----
    {
        const float4* D4 = reinterpret_cast<const float4*>(D + (size_t)bb * 65536);
        for (int k = 0; k < 32; ++k) {
            int idx4 = tid + (k << 9);            // 64 float4 per row -> wave == one row
            float4 d = D4[idx4];
            int i = idx4 >> 6;
            int j = (idx4 & 63) << 2;
            float v0[4] = {d.x, d.y, d.z, d.w};
            float k0[4];
            #pragma unroll
            for (int q = 0; q < 4; ++q) {
                float c = cosf(fminf(v0[q] * 2.0f, 1.57079632679489662f)) + 1e-5f;
                k0[q] = expf(20.0f * logf(c));    // == exp(-C/eps)
            }
            __half2 h01 = { __float2half(k0[0]), __float2half(k0[1]) };
            __half2 h23 = { __float2half(k0[2]), __float2half(k0[3]) };
            uint2 wv;
            wv.x = *reinterpret_cast<unsigned int*>(&h01);
            wv.y = *reinterpret_cast<unsigned int*>(&h23);
            int off = (i << 9) + (((j << 1) ^ ((i & 31) << 4)));
            *reinterpret_cast<uint2*>(Kbytes + off) = wv;
        }
    }
    if (tid < 256) {
        sh_bf[tid] = 1.0f;
        sh_bh[tid] = __float2half(1.0f);
    }
    __syncthreads();

    const int lane = tid & 63;
    const int wv   = tid >> 6;        // 8 waves
    const int lr   = lane & 15;       // A-row / B-col lane selector
    const int lg   = lane >> 4;       // k-group (8 contiguous elements each)
    const int rowbase = wv << 5;      // 32 rows (or cols) per wave

    // ---- stage persistent A-fragments ----
    half8 afr[2][8];                  // K row-blocks: rows rowbase+blk*16+lr
    #pragma unroll
    for (int blk = 0; blk < 2; ++blk) {
        int R = rowbase + (blk << 4) + lr;
        const char* Krow = Kbytes + (R << 9);
        int swz = (R & 31) << 4;
        #pragma unroll
        for (int ch = 0; ch < 8; ++ch)
            afr[blk][ch] = *reinterpret_cast<const half8*>(
                Krow + (((ch << 6) + (lg << 4)) ^ swz));
    }
    half8 afc[2][8];                  // K^T col-blocks: col rowbase+blk*16+lr
    #pragma unroll
    for (int blk = 0; blk < 2; ++blk) {
        int C = rowbase + (blk << 4) + lr;
        #pragma unroll
        for (int ch = 0; ch < 8; ++ch) {
            half8 v;
            #pragma unroll
            for (int j = 0; j < 8; ++j) {
                int i = (ch << 5) + (lg << 3) + j;
                unsigned short u = *reinterpret_cast<const unsigned short*>(
                    Kbytes + (i << 9) + (((C << 1) ^ ((i & 31) << 4))));
                v[j] = __builtin_bit_cast(_Float16, u);
            }
            afc[blk][ch] = v;
        }
    }

    for (int it = 0; it < NITERS; ++it) {
        // ---------- row phase: s_i = mean_j K0[i][j]*b[j] via MFMA ----------
        {
            half8 bfr[8];
            #pragma unroll
            for (int ch = 0; ch < 8; ++ch)
                bfr[ch] = *reinterpret_cast<const half8*>(
                    reinterpret_cast<const char*>(sh_bh) + (ch << 6) + (lg << 4));
            f32x4 acc0 = {0.f,0.f,0.f,0.f}, acc1 = {0.f,0.f,0.f,0.f};
            #pragma unroll
            for (int ch = 0; ch < 8; ++ch) {
                acc0 = __builtin_amdgcn_mfma_f32_16x16x32_f16(afr[0][ch], bfr[ch], acc0, 0, 0, 0);
                acc1 = __builtin_amdgcn_mfma_f32_16x16x32_f16(afr[1][ch], bfr[ch], acc1, 0, 0, 0);
            }
            if (lr == 0) {                     // D: col=lane&15, row=(lane>>4)*4+q
                #pragma unroll
                for (int q = 0; q < 4; ++q) {
                    int   R0 = rowbase + (lg << 2) + q;
                    float s0 = acc0[q] * (1.0f / 256.0f);
                    float a0 = fminf(__powf(s0, -(1.0f / 1.1f)), 1e30f);
                    sh_ah[R0] = __float2half(a0);
                    sh_af[R0] = a0;
                    int   R1 = R0 + 16;
                    float s1 = acc1[q] * (1.0f / 256.0f);
                    float a1 = fminf(__powf(s1, -(1.0f / 1.1f)), 1e30f);
                    sh_ah[R1] = __float2half(a1);
                    sh_af[R1] = a1;
                }
            }
        }
        __syncthreads();
        // ---------- col phase: s2_j = mean_i K0[i][j]*a[i] via MFMA ----------
        {
            half8 afrg[8];
            #pragma unroll
            for (int ch = 0; ch < 8; ++ch)
                afrg[ch] = *reinterpret_cast<const half8*>(
                    reinterpret_cast<const char*>(sh_ah) + (ch << 6) + (lg << 4));
            f32x4 acc0 = {0.f,0.f,0.f,0.f}, acc1 = {0.f,0.f,0.f,0.f};
            #pragma unroll
            for (int ch = 0; ch < 8; ++ch) {
                acc0 = __builtin_amdgcn_mfma_f32_16x16x32_f16(afc[0][ch], afrg[ch], acc0, 0, 0, 0);
                acc1 = __builtin_amdgcn_mfma_f32_16x16x32_f16(afc[1][ch], afrg[ch], acc1, 0, 0, 0);
            }
            if (lr == 0) {
                #pragma unroll
                for (int q = 0; q < 4; ++q) {
                    int   C0 = rowbase + (lg << 2) + q;
                    float s20 = acc0[q] * (1.0f / 256.0f);
                    float b0  = fminf(__powf(s20, -(1.0f / 1.1f)), 1e30f);
                    sh_bh[C0] = __float2half(b0);
                    sh_bf[C0] = b0;
                    sh_s2[C0] = s20;
                    int   C1 = C0 + 16;
                    float s21 = acc1[q] * (1.0f / 256.0f);
                    float b1  = fminf(__powf(s21, -(1.0f / 1.1f)), 1e30f);
                    sh_bh[C1] = __float2half(b1);
                    sh_bf[C1] = b1;
                    sh_s2[C1] = s21;
                }
            }
        }
        __syncthreads();
    }

    // ---- epilogue: K_fin = K0*a_i*b_j ; C = -0.1*ln(K0) ----
    float val = 0.0f;
    #pragma unroll
    for (int blk = 0; blk < 2; ++blk) {
        float s = 0.0f, tp = 0.0f;
        #pragma unroll
        for (int ch = 0; ch < 8; ++ch) {
            const float* bp = sh_bf + (ch << 5) + (lg << 3);
            float4 b0 = *reinterpret_cast<const float4*>(bp);
            float4 b1 = *reinterpret_cast<const float4*>(bp + 4);
            float bf[8] = {b0.x, b0.y, b0.z, b0.w, b1.x, b1.y, b1.z, b1.w};
            #pragma unroll
            for (int j = 0; j < 8; ++j) {
                float kf   = (float)afr[blk][ch][j];
                float prod = kf * bf[j];
                s += prod;
                float cl = (kf > 0.0f) ? (-0.1f * __logf(kf)) : 0.0f;
                tp = fmaf(prod, cl, tp);
            }
        }
        // rows are shared by the 4 lanes {lr, lr+16, lr+32, lr+48}
        s  += __shfl_xor(s, 16, 64);  s  += __shfl_xor(s, 32, 64);
        tp += __shfl_xor(tp, 16, 64); tp += __shfl_xor(tp, 32, 64);
        int   R = rowbase + (blk << 4) + lr;
        float a = sh_af[R];
        float row_marg = a * s * (1.0f / 256.0f);
        float d1  = row_marg / (1.0f + 1e-10f);
        float kl1 = d1 * __logf(d1 + 1e-10f) - d1 + 1.0f;
        val += 0.25f * (kl1 * (1.0f / 256.0f) + (a * tp) * (1.0f / 65536.0f));
    }
    if (tid < 256) {
        float cm  = sh_bf[tid] * sh_s2[tid];      // b_j * mean_i K0*a
        float d2  = cm / (1.0f + 1e-10f);
        float kl2 = d2 * __logf(d2 + 1e-10f) - d2 + 1.0f;
        val += kl2 * (1.0f / 256.0f);
    }

    // ---- reduce 512 -> 1 ----
    #pragma unroll
    for (int off = 32; off > 0; off >>= 1)
        val += __shfl_down(val, off, 64);
    if ((tid & 63) == 0) part[tid >> 6] = val;
    __syncthreads();
    if (tid == 0) {
        float t = 0.0f;
        #pragma unroll
        for (int w = 0; w < 8; ++w) t += part[w];
        out[bb] = t;
    }
}

extern "C" void kernel_launch(void* const* d_in, const int* in_sizes, int n_in,
                              void* d_out, int out_size, void* d_ws, size_t ws_size,
                              hipStream_t stream) {
    (void)in_sizes; (void)n_in; (void)d_ws; (void)ws_size; (void)out_size;
    const float* D = reinterpret_cast<const float*>(d_in[0]);
    float* out     = reinterpret_cast<float*>(d_out);
    wfr_kernel<<<dim3(256), dim3(512), 0, stream>>>(D, out);
}